// Round 10
// baseline (706.554 us; speedup 1.0000x reference)
//
#include <hip/hip_runtime.h>
#include <math.h>

#define KDIM 1024
#define HID 256
#define NE 16
#define ROWS_BLK 32
#define KCH 32
#define NCHUNK 32
#define CH_BYTES 32768            // B chunk image: [p][kg][col] 16B granules
#define W2T_PLANE (NE * HID)
#define ABUF(i) ((i) * 4096)      // 2 x 4KB A dbuf @0 ([p][kg][row32] granules)
#define SMEM_BYTES 32768          // epilogue h-planes overlay (2 x 16KB)

typedef __attribute__((ext_vector_type(4))) _Float16 f16x4;
typedef __attribute__((ext_vector_type(8))) _Float16 f16x8;
typedef __attribute__((ext_vector_type(16))) float f32x16;
typedef __attribute__((ext_vector_type(4))) float f32x4;

// R3/R6-R9-proven planes: p1 = fl16(v), p2 = fl16((v - p1)*4096).
__global__ void prep_w1(const float* __restrict__ W1, _Float16* __restrict__ img) {
  int idx = blockIdx.x * 256 + threadIdx.x;   // 0..32767
  int col = idx & 255, kgl = idx >> 8;        // kgl 0..127
  int c = kgl >> 2, kg = kgl & 3, k8 = kgl * 8;
  f16x8 p1, p2;
#pragma unroll
  for (int i = 0; i < 8; ++i) {
    float v = W1[(size_t)(k8 + i) * HID + col];
    _Float16 a = (_Float16)v;
    _Float16 b = (_Float16)((v - (float)a) * 4096.0f);
    p1[i] = a; p2[i] = b;
  }
  size_t off = (size_t)c * 16384 + (size_t)kg * 2048 + (size_t)col * 8;  // shorts
  *(f16x8*)(img + off) = p1;
  *(f16x8*)(img + off + 8192) = p2;
}

__global__ void prep_w2(const float* __restrict__ W2, _Float16* __restrict__ w2t) {
  int idx = blockIdx.x * 256 + threadIdx.x;   // 0..4095
  int e = idx & 15, k = idx >> 4;
  float v = W2[(size_t)k * NE + e];
  _Float16 a = (_Float16)v;
  _Float16 b = (_Float16)((v - (float)a) * 4096.0f);
  w2t[(size_t)e * HID + k] = a;
  w2t[W2T_PLANE + (size_t)e * HID + k] = b;
}

__global__ __launch_bounds__(256, 3) void fused_router(
    const float* __restrict__ x, const _Float16* __restrict__ w1img,
    const _Float16* __restrict__ w2t, const float* __restrict__ bias1,
    const float* __restrict__ bias2, float* __restrict__ outA,
    float* __restrict__ outL)
{
  extern __shared__ char smem[];
  const int t = threadIdx.x, l = t & 63, w = t >> 6;   // 4 waves, colg = w
  const int l31 = l & 31, hi = l >> 5;
  const int R0 = blockIdx.x * ROWS_BLK;
  const int bcol0 = w * 64 + l31;            // + 32*ct

  // x loader: row = t&31, quad q = t>>5 (0..7): kg = q>>1, half = q&1
  const int xrow = t & 31, xq = t >> 5;
  const int xkg = xq >> 1, xhalf = xq & 1;
  const float* xbase = x + (size_t)(R0 + xrow) * KDIM + xkg * 8 + xhalf * 4;

  // per-lane B base inside a chunk image: + p*16384 + (2s+hi)*4096 + col*16
  const char* bimg = (const char*)w1img + (size_t)bcol0 * 16 + (size_t)hi * 4096;

  f32x16 acc0[2], accA[2];
#pragma unroll
  for (int ct = 0; ct < 2; ++ct)
#pragma unroll
    for (int j = 0; j < 16; ++j) { acc0[ct][j] = 0.f; accA[ct][j] = 0.f; }

  float4 xvA, xvB;
  f16x8 bsetA[8], bsetB[8];   // [4*s + 2*ct + p], static indices only

#define XLOADV(XV_, C_) do {                                                  \
    XV_ = *(const float4*)(xbase + (size_t)(C_) * KCH);                       \
  } while (0)

#define BLOADR(BS_, C_) do {                                                  \
    const char* bp_ = bimg + (size_t)(C_) * CH_BYTES;                         \
    _Pragma("unroll") for (int i_ = 0; i_ < 8; ++i_) {                        \
      const int off_ = ((i_ >> 2) & 1) * 8192 + ((i_ >> 1) & 1) * 512         \
                     + (i_ & 1) * 16384;                                      \
      BS_[i_] = *(const f16x8*)(bp_ + off_);                                  \
    }                                                                         \
  } while (0)

#define ASPLITV(XV_, ABW_) do {                                               \
    float vals_[4] = {(XV_).x, (XV_).y, (XV_).z, (XV_).w};                    \
    f16x4 pa_, pb_;                                                           \
    _Pragma("unroll") for (int j_ = 0; j_ < 4; ++j_) {                        \
      float v_ = vals_[j_];                                                   \
      _Float16 a_ = (_Float16)v_;                                             \
      _Float16 b_ = (_Float16)((v_ - (float)a_) * 4096.0f);                   \
      pa_[j_] = a_; pb_[j_] = b_;                                             \
    }                                                                         \
    int ao_ = ABUF(ABW_) + xkg * 512 + xrow * 16 + xhalf * 8;                 \
    *(f16x4*)(smem + ao_) = pa_;                                              \
    *(f16x4*)(smem + ao_ + 2048) = pb_;                                       \
  } while (0)

#define COMPUTE(AR_, BS_) do {                                                \
    _Pragma("unroll") for (int s_ = 0; s_ < 2; ++s_) {                        \
      const int gg_ = 2 * s_ + hi;                                            \
      int ao_ = ABUF(AR_) + gg_ * 512 + l31 * 16;                             \
      f16x8 a1_ = *(const f16x8*)(smem + ao_);                                \
      f16x8 a2_ = *(const f16x8*)(smem + ao_ + 2048);                         \
      __builtin_amdgcn_s_setprio(1);                                          \
      _Pragma("unroll") for (int ct_ = 0; ct_ < 2; ++ct_)                     \
        acc0[ct_] = __builtin_amdgcn_mfma_f32_32x32x16_f16(                   \
            a1_, BS_[4 * s_ + 2 * ct_ + 0], acc0[ct_], 0, 0, 0);              \
      _Pragma("unroll") for (int ct_ = 0; ct_ < 2; ++ct_)                     \
        accA[ct_] = __builtin_amdgcn_mfma_f32_32x32x16_f16(                   \
            a1_, BS_[4 * s_ + 2 * ct_ + 1], accA[ct_], 0, 0, 0);              \
      _Pragma("unroll") for (int ct_ = 0; ct_ < 2; ++ct_)                     \
        accA[ct_] = __builtin_amdgcn_mfma_f32_32x32x16_f16(                   \
            a2_, BS_[4 * s_ + 2 * ct_ + 0], accA[ct_], 0, 0, 0);              \
      __builtin_amdgcn_s_setprio(0);                                          \
    }                                                                         \
  } while (0)

#define BODY(C_, AR_, AW_, BCUR_, BNXT_, XC_, XL_) do {                       \
    if ((C_) + 1 < NCHUNK) BLOADR(BNXT_, (C_) + 1);                           \
    if ((C_) + 2 < NCHUNK) XLOADV(XL_, (C_) + 2);                             \
    if ((C_) + 1 < NCHUNK) ASPLITV(XC_, AW_);                                 \
    COMPUTE(AR_, BCUR_);                                                      \
    asm volatile("s_waitcnt lgkmcnt(0)" ::: "memory");                        \
    __builtin_amdgcn_s_barrier();                                             \
  } while (0)

  // ---- prologue ----
  XLOADV(xvA, 0);
  BLOADR(bsetA, 0);
  XLOADV(xvB, 1);
  ASPLITV(xvA, 0);
  asm volatile("s_waitcnt lgkmcnt(0)" ::: "memory");
  __builtin_amdgcn_s_barrier();

  // ---- main loop: period-2 static buffer/regset pattern ----
#pragma unroll 1
  for (int cb = 0; cb < NCHUNK; cb += 2) {
    BODY(cb,     0, 1, bsetA, bsetB, xvB, xvA);
    BODY(cb + 1, 1, 0, bsetB, bsetA, xvA, xvB);
  }

  // ---- epilogue: single 32-row pass ----
  const float c12 = 1.0f / 4096.0f;
  const int tok = l & 15, g2 = l >> 4;

  __syncthreads();
#pragma unroll
  for (int ct = 0; ct < 2; ++ct) {
    int col = bcol0 + 32 * ct;
    float bc = bias1[col];
    int cg = col >> 3, cb = (col & 7) * 2;
#pragma unroll
    for (int r = 0; r < 16; ++r) {
      int tloc = (r & 3) + 8 * (r >> 2) + 4 * hi;   // 0..31
      float v = acc0[ct][r] + c12 * accA[ct][r] + bc;
      v = v > 0.f ? v : expm1f(v);
      _Float16 h1 = (_Float16)v;
      _Float16 h2 = (_Float16)((v - (float)h1) * 4096.0f);
      int off = tloc * 512 + ((cg ^ (tloc & 7)) << 4) + cb;
      *(_Float16*)(smem + off) = h1;
      *(_Float16*)(smem + 16384 + off) = h2;
    }
  }
  __syncthreads();

  if (w < 2) {
    int tloc = w * 16 + tok;                 // 0..31
    f32x4 L0, LA;
#pragma unroll
    for (int j = 0; j < 4; ++j) { L0[j] = 0.f; LA[j] = 0.f; }
    const _Float16* w2a = w2t + (size_t)tok * HID;
    const _Float16* w2b = w2a + W2T_PLANE;
#pragma unroll
    for (int kt = 0; kt < 8; ++kt) {
      int gg = (kt * 4 + g2) ^ (tloc & 7);
      f16x8 hb1 = *(const f16x8*)(smem + tloc * 512 + (gg << 4));
      f16x8 hb2 = *(const f16x8*)(smem + 16384 + tloc * 512 + (gg << 4));
      f16x8 wa = *(const f16x8*)(w2a + kt * 32 + 8 * g2);
      f16x8 wb = *(const f16x8*)(w2b + kt * 32 + 8 * g2);
      L0 = __builtin_amdgcn_mfma_f32_16x16x32_f16(wa, hb1, L0, 0, 0, 0);
      LA = __builtin_amdgcn_mfma_f32_16x16x32_f16(wa, hb2, LA, 0, 0, 0);
      LA = __builtin_amdgcn_mfma_f32_16x16x32_f16(wb, hb1, LA, 0, 0, 0);
    }
    float4 b2v = *(const float4*)(bias2 + 4 * g2);
    float L[4];
    L[0] = L0[0] + c12 * LA[0] + b2v.x;
    L[1] = L0[1] + c12 * LA[1] + b2v.y;
    L[2] = L0[2] + c12 * LA[2] + b2v.z;
    L[3] = L0[3] + c12 * LA[3] + b2v.w;

    float o1[4], o2[4], o3[4];
#pragma unroll
    for (int j = 0; j < 4; ++j) o1[j] = __shfl_xor(L[j], 16);
#pragma unroll
    for (int j = 0; j < 4; ++j) o2[j] = __shfl_xor(L[j], 32);
#pragma unroll
    for (int j = 0; j < 4; ++j) o3[j] = __shfl_xor(o1[j], 32);

    float all16[16];
#pragma unroll
    for (int cq = 0; cq < 4; ++cq) {
      int xg = cq ^ g2;
#pragma unroll
      for (int j = 0; j < 4; ++j) {
        float v = L[j];
        v = (xg == 1) ? o1[j] : v;
        v = (xg == 2) ? o2[j] : v;
        v = (xg == 3) ? o3[j] : v;
        all16[cq * 4 + j] = v;
      }
    }

    int i1 = 0; float m1 = all16[0];
#pragma unroll
    for (int e = 1; e < 16; ++e) { if (all16[e] > m1) { m1 = all16[e]; i1 = e; } }
    int i2 = -1; float m2 = -INFINITY;
#pragma unroll
    for (int e = 0; e < 16; ++e) { if (e != i1 && all16[e] > m2) { m2 = all16[e]; i2 = e; } }
    float ex = expf(m2 - m1);
    float sden = 1.f + ex;
    float A1 = 1.f / sden;
    float A2 = ex / sden;

    int e0 = 4 * g2;
    float4 alv;
    alv.x = (e0 + 0 == i1) ? A1 : ((e0 + 0 == i2) ? A2 : 0.f);
    alv.y = (e0 + 1 == i1) ? A1 : ((e0 + 1 == i2) ? A2 : 0.f);
    alv.z = (e0 + 2 == i1) ? A1 : ((e0 + 2 == i2) ? A2 : 0.f);
    alv.w = (e0 + 3 == i1) ? A1 : ((e0 + 3 == i2) ? A2 : 0.f);

    size_t orow = (size_t)(R0 + tloc);
    float4 lgv; lgv.x = L[0]; lgv.y = L[1]; lgv.z = L[2]; lgv.w = L[3];
    *(float4*)(outL + orow * NE + e0) = lgv;
    *(float4*)(outA + orow * NE + e0) = alv;
  }
#undef XLOADV
#undef BLOADR
#undef ASPLITV
#undef COMPUTE
#undef BODY
}

extern "C" void kernel_launch(void* const* d_in, const int* in_sizes, int n_in,
                              void* d_out, int out_size, void* d_ws, size_t ws_size,
                              hipStream_t stream) {
  const float* x  = (const float*)d_in[0];
  const float* W1 = (const float*)d_in[1];
  const float* b1 = (const float*)d_in[2];
  const float* W2 = (const float*)d_in[3];
  const float* b2 = (const float*)d_in[4];
  _Float16* w1img = (_Float16*)d_ws;
  _Float16* w2t = w1img + (size_t)NCHUNK * (CH_BYTES / 2);
  float* outA = (float*)d_out;
  const size_t n_tok = (size_t)in_sizes[0] / KDIM;
  float* outL = outA + n_tok * NE;

  prep_w1<<<dim3(128), dim3(256), 0, stream>>>(W1, w1img);
  prep_w2<<<dim3(16), dim3(256), 0, stream>>>(W2, w2t);

  hipFuncSetAttribute((const void*)fused_router,
                      hipFuncAttributeMaxDynamicSharedMemorySize, SMEM_BYTES);
  fused_router<<<dim3((unsigned)(n_tok / ROWS_BLK)), dim3(256), SMEM_BYTES, stream>>>(
      x, w1img, w2t, b1, b2, outA, outL);
}

// Round 12
// 627.570 us; speedup vs baseline: 1.1259x; 1.1259x over previous
//
#include <hip/hip_runtime.h>
#include <math.h>

#define KDIM 1024
#define HID 256
#define NE 16
#define ROWS_BLK 128
#define KCH 32
#define NCHUNK 32
#define CH_BYTES 32768            // B chunk image: [p][kg][col] 16B granules
#define W2T_PLANE (NE * HID)
#define ABUF(i) ((i) * 16384)     // 2 x 16KB A dbuf @0
#define BBASE 32768               // 2 x 32KB B dbuf @32768
#define BB_STRIDE 32768
#define SMEM_BYTES 98304

typedef __attribute__((ext_vector_type(8))) _Float16 f16x8;
typedef __attribute__((ext_vector_type(16))) float f32x16;
typedef __attribute__((ext_vector_type(4))) float f32x4;

__device__ __forceinline__ void gld16(const void* g, void* s) {
  __builtin_amdgcn_global_load_lds(
      (const __attribute__((address_space(1))) void*)g,
      (__attribute__((address_space(3))) void*)s, 16, 0, 0);
}

// R3/R6-R10-proven planes: p1 = fl16(v), p2 = fl16((v - p1)*4096).
__global__ void prep_w1(const float* __restrict__ W1, _Float16* __restrict__ img) {
  int idx = blockIdx.x * 256 + threadIdx.x;   // 0..32767
  int col = idx & 255, kgl = idx >> 8;        // kgl 0..127
  int c = kgl >> 2, kg = kgl & 3, k8 = kgl * 8;
  f16x8 p1, p2;
#pragma unroll
  for (int i = 0; i < 8; ++i) {
    float v = W1[(size_t)(k8 + i) * HID + col];
    _Float16 a = (_Float16)v;
    _Float16 b = (_Float16)((v - (float)a) * 4096.0f);
    p1[i] = a; p2[i] = b;
  }
  size_t off = (size_t)c * 16384 + (size_t)kg * 2048 + (size_t)col * 8;  // shorts
  *(f16x8*)(img + off) = p1;
  *(f16x8*)(img + off + 8192) = p2;
}

__global__ void prep_w2(const float* __restrict__ W2, _Float16* __restrict__ w2t) {
  int idx = blockIdx.x * 256 + threadIdx.x;   // 0..4095
  int e = idx & 15, k = idx >> 4;
  float v = W2[(size_t)k * NE + e];
  _Float16 a = (_Float16)v;
  _Float16 b = (_Float16)((v - (float)a) * 4096.0f);
  w2t[(size_t)e * HID + k] = a;
  w2t[W2T_PLANE + (size_t)e * HID + k] = b;
}

__global__ __launch_bounds__(512, 2) void fused_router(
    const float* __restrict__ x, const _Float16* __restrict__ w1img,
    const _Float16* __restrict__ w2t, const float* __restrict__ bias1,
    const float* __restrict__ bias2, float* __restrict__ outA,
    float* __restrict__ outL)
{
  extern __shared__ char smem[];
  const int t = threadIdx.x, l = t & 63, w = t >> 6;
  const int rowg = w >> 2, colg = w & 3;     // 2 x 4 waves: 128 rows x 256 cols
  const int l31 = l & 31, hi = l >> 5;
  const int R0 = blockIdx.x * ROWS_BLK;
  const int arow0 = rowg * 64 + l31;         // + 32*rt
  const int bcol0 = colg * 64 + l31;         // + 32*ct

  // x loader: row xr = t>>2 (0..127), granule xq = t&3 (k = xq*8..+7)
  const int xr = t >> 2, xq = t & 3;
  const float* xbase = x + (size_t)(R0 + xr) * KDIM + xq * 8;

  // B stager: thread t copies image bytes t*16 (+half*16384, +8192)
  const char* ibase = (const char*)w1img + t * 16;

  f32x16 acc0[2][2], accA[2][2];
#pragma unroll
  for (int rt = 0; rt < 2; ++rt)
#pragma unroll
    for (int ct = 0; ct < 2; ++ct)
#pragma unroll
      for (int j = 0; j < 16; ++j) { acc0[rt][ct][j] = 0.f; accA[rt][ct][j] = 0.f; }

  float xvA[8], xvB[8];

#define XLOADV(XV_, C_) do {                                                  \
    *(float4*)(XV_)     = *(const float4*)(xbase + (size_t)(C_) * KCH);       \
    *(float4*)((XV_)+4) = *(const float4*)(xbase + (size_t)(C_) * KCH + 4);   \
  } while (0)

#define ASPLITV(XV_, ABW_) do {                                               \
    f16x8 pa_, pb_;                                                           \
    _Pragma("unroll") for (int j_ = 0; j_ < 8; ++j_) {                        \
      float v_ = (XV_)[j_];                                                   \
      _Float16 a_ = (_Float16)v_;                                             \
      _Float16 b_ = (_Float16)((v_ - (float)a_) * 4096.0f);                   \
      pa_[j_] = a_; pb_[j_] = b_;                                             \
    }                                                                         \
    int ao_ = ABUF(ABW_) + xq * 2048 + xr * 16;                               \
    *(f16x8*)(smem + ao_) = pa_;                                              \
    *(f16x8*)(smem + ao_ + 8192) = pb_;                                       \
  } while (0)

#define BSTAGE_H(C1_, BUF_, H_) do {                                          \
    const char* is_ = ibase + (size_t)(C1_) * CH_BYTES + (H_) * 16384;        \
    char* bd_ = smem + BBASE + (BUF_) * BB_STRIDE + (H_) * 16384 + t * 16;    \
    gld16(is_,        bd_);                                                   \
    gld16(is_ + 8192, bd_ + 8192);                                            \
  } while (0)

#define FRAG_READ(PI_, S_)                                                    \
    f16x8 a1_[2], a2_[2], b1_[2], b2_[2];                                     \
    {                                                                         \
      const int gg_ = 2 * (S_) + hi;                                          \
      _Pragma("unroll") for (int rt_ = 0; rt_ < 2; ++rt_) {                   \
        int ao_ = ABUF(PI_) + gg_ * 2048 + (arow0 + 32 * rt_) * 16;           \
        a1_[rt_] = *(const f16x8*)(smem + ao_);                               \
        a2_[rt_] = *(const f16x8*)(smem + ao_ + 8192);                        \
      }                                                                       \
      _Pragma("unroll") for (int ct_ = 0; ct_ < 2; ++ct_) {                   \
        int bo_ = BBASE + (PI_) * BB_STRIDE + gg_ * 4096                      \
                  + (bcol0 + 32 * ct_) * 16;                                  \
        b1_[ct_] = *(const f16x8*)(smem + bo_);                               \
        b2_[ct_] = *(const f16x8*)(smem + bo_ + 16384);                       \
      }                                                                       \
    }

#define MFMA12() do {                                                         \
    __builtin_amdgcn_s_setprio(1);                                            \
    _Pragma("unroll") for (int ct_ = 0; ct_ < 2; ++ct_)                       \
    _Pragma("unroll") for (int rt_ = 0; rt_ < 2; ++rt_) {                     \
      acc0[rt_][ct_] = __builtin_amdgcn_mfma_f32_32x32x16_f16(                \
          a1_[rt_], b1_[ct_], acc0[rt_][ct_], 0, 0, 0);                       \
      accA[rt_][ct_] = __builtin_amdgcn_mfma_f32_32x32x16_f16(                \
          a1_[rt_], b2_[ct_], accA[rt_][ct_], 0, 0, 0);                       \
      accA[rt_][ct_] = __builtin_amdgcn_mfma_f32_32x32x16_f16(                \
          a2_[rt_], b1_[ct_], accA[rt_][ct_], 0, 0, 0);                       \
    }                                                                         \
    __builtin_amdgcn_s_setprio(0);                                            \
  } while (0)

// Phase 0 of chunk C_ (parity PI_): s=0 frags + stage B(C_+1) half0. NO vmcnt.
#define PH0(C_, PI_, STG_) do {                                               \
    FRAG_READ(PI_, 0)                                                         \
    if (STG_) BSTAGE_H((C_) + 1, (PI_) ^ 1, 0);                               \
    __builtin_amdgcn_s_barrier();                                             \
    asm volatile("s_waitcnt lgkmcnt(0)" ::: "memory");                        \
    __builtin_amdgcn_sched_barrier(0);                                        \
    MFMA12();                                                                 \
    __builtin_amdgcn_s_barrier();                                             \
  } while (0)

// Phase 1 of chunk C_: s=1 frags + stage B(C_+1) h1 + ASPLIT(C_+1) + XLOAD(C_+2).
// OWN vmcnt gate BEFORE the final barrier: certifies this wave's B(C_+1) gld16s
// landed; the barrier then publishes to all readers of chunk C_+1.
#define PH1(C_, PI_, STG_, XNXT_, XL_, XLD_, VMSTR_) do {                     \
    FRAG_READ(PI_, 1)                                                         \
    if (STG_) {                                                               \
      BSTAGE_H((C_) + 1, (PI_) ^ 1, 1);                                       \
      ASPLITV(XNXT_, (PI_) ^ 1);                                              \
    }                                                                         \
    __builtin_amdgcn_sched_barrier(0);                                        \
    if (XL_) XLOADV(XLD_, (C_) + 2);                                          \
    __builtin_amdgcn_sched_barrier(0);                                        \
    __builtin_amdgcn_s_barrier();                                             \
    asm volatile("s_waitcnt lgkmcnt(0)" ::: "memory");                        \
    __builtin_amdgcn_sched_barrier(0);                                        \
    MFMA12();                                                                 \
    __builtin_amdgcn_sched_barrier(0);                                        \
    asm volatile("s_waitcnt vmcnt(" VMSTR_ ")" ::: "memory");                 \
    __builtin_amdgcn_sched_barrier(0);                                        \
    __builtin_amdgcn_s_barrier();                                             \
  } while (0)

  // ---- prologue: x(0),x(1); B(0)->bbuf0; A(0)->abuf0; gate BEFORE barrier ----
  XLOADV(xvA, 0);
  XLOADV(xvB, 1);
  BSTAGE_H(0, 0, 0);
  BSTAGE_H(0, 0, 1);
  ASPLITV(xvA, 0);
  asm volatile("s_waitcnt vmcnt(0)" ::: "memory");    // B(0) landed (x1 too)
  asm volatile("s_waitcnt lgkmcnt(0)" ::: "memory");  // A(0) writes retired
  __builtin_amdgcn_sched_barrier(0);
  __builtin_amdgcn_s_barrier();

  // ---- main loop: chunks 0..29 steady, peel 30,31 ----
#pragma unroll 1
  for (int cb = 0; cb < NCHUNK - 2; cb += 2) {
    PH0(cb, 0, 1);
    PH1(cb, 0, 1, xvB, 1, xvA, "2");
    PH0(cb + 1, 1, 1);
    PH1(cb + 1, 1, 1, xvA, 1, xvB, "2");
  }
  PH0(30, 0, 1);
  PH1(30, 0, 1, xvB, 0, xvA, "0");    // stages B(31)+A(31); all must land
  PH0(31, 1, 0);
  PH1(31, 1, 0, xvA, 0, xvB, "0");

  // ---- epilogue: two R7-verified 64-row passes ----
  const float c12 = 1.0f / 4096.0f;
  const int tok = l & 15, g2 = l >> 4;

#pragma unroll 1
  for (int p = 0; p < 2; ++p) {
    __syncthreads();
    if (rowg == p) {
#pragma unroll
      for (int ct = 0; ct < 2; ++ct) {
        int col = bcol0 + 32 * ct;
        float bc = bias1[col];
        int cg = col >> 3, cb = (col & 7) * 2;
#pragma unroll
        for (int rt = 0; rt < 2; ++rt) {
#pragma unroll
          for (int r = 0; r < 16; ++r) {
            int tloc = 32 * rt + (r & 3) + 8 * (r >> 2) + 4 * hi;   // 0..63
            float v = acc0[rt][ct][r] + c12 * accA[rt][ct][r] + bc;
            v = v > 0.f ? v : expm1f(v);
            _Float16 h1 = (_Float16)v;
            _Float16 h2 = (_Float16)((v - (float)h1) * 4096.0f);
            int off = tloc * 512 + ((cg ^ (tloc & 7)) << 4) + cb;
            *(_Float16*)(smem + off) = h1;
            *(_Float16*)(smem + 32768 + off) = h2;
          }
        }
      }
    }
    __syncthreads();
    if (w < 4) {
      int tloc = w * 16 + tok;               // 0..63
      f32x4 L0, LA;
#pragma unroll
      for (int j = 0; j < 4; ++j) { L0[j] = 0.f; LA[j] = 0.f; }
      const _Float16* w2a = w2t + (size_t)tok * HID;
      const _Float16* w2b = w2a + W2T_PLANE;
#pragma unroll
      for (int kt = 0; kt < 8; ++kt) {
        int gg = (kt * 4 + g2) ^ (tloc & 7);
        f16x8 hb1 = *(const f16x8*)(smem + tloc * 512 + (gg << 4));
        f16x8 hb2 = *(const f16x8*)(smem + 32768 + tloc * 512 + (gg << 4));
        f16x8 wa = *(const f16x8*)(w2a + kt * 32 + 8 * g2);
        f16x8 wb = *(const f16x8*)(w2b + kt * 32 + 8 * g2);
        L0 = __builtin_amdgcn_mfma_f32_16x16x32_f16(wa, hb1, L0, 0, 0, 0);
        LA = __builtin_amdgcn_mfma_f32_16x16x32_f16(wa, hb2, LA, 0, 0, 0);
        LA = __builtin_amdgcn_mfma_f32_16x16x32_f16(wb, hb1, LA, 0, 0, 0);
      }
      float4 b2v = *(const float4*)(bias2 + 4 * g2);
      float L[4];
      L[0] = L0[0] + c12 * LA[0] + b2v.x;
      L[1] = L0[1] + c12 * LA[1] + b2v.y;
      L[2] = L0[2] + c12 * LA[2] + b2v.z;
      L[3] = L0[3] + c12 * LA[3] + b2v.w;

      float o1[4], o2[4], o3[4];
#pragma unroll
      for (int j = 0; j < 4; ++j) o1[j] = __shfl_xor(L[j], 16);
#pragma unroll
      for (int j = 0; j < 4; ++j) o2[j] = __shfl_xor(L[j], 32);
#pragma unroll
      for (int j = 0; j < 4; ++j) o3[j] = __shfl_xor(o1[j], 32);

      float all16[16];
#pragma unroll
      for (int cq = 0; cq < 4; ++cq) {
        int xg = cq ^ g2;
#pragma unroll
        for (int j = 0; j < 4; ++j) {
          float v = L[j];
          v = (xg == 1) ? o1[j] : v;
          v = (xg == 2) ? o2[j] : v;
          v = (xg == 3) ? o3[j] : v;
          all16[cq * 4 + j] = v;
        }
      }

      int i1 = 0; float m1 = all16[0];
#pragma unroll
      for (int e = 1; e < 16; ++e) { if (all16[e] > m1) { m1 = all16[e]; i1 = e; } }
      int i2 = -1; float m2 = -INFINITY;
#pragma unroll
      for (int e = 0; e < 16; ++e) { if (e != i1 && all16[e] > m2) { m2 = all16[e]; i2 = e; } }
      float ex = expf(m2 - m1);
      float sden = 1.f + ex;
      float A1 = 1.f / sden;
      float A2 = ex / sden;

      int e0 = 4 * g2;
      float4 alv;
      alv.x = (e0 + 0 == i1) ? A1 : ((e0 + 0 == i2) ? A2 : 0.f);
      alv.y = (e0 + 1 == i1) ? A1 : ((e0 + 1 == i2) ? A2 : 0.f);
      alv.z = (e0 + 2 == i1) ? A1 : ((e0 + 2 == i2) ? A2 : 0.f);
      alv.w = (e0 + 3 == i1) ? A1 : ((e0 + 3 == i2) ? A2 : 0.f);

      size_t orow = (size_t)(R0 + p * 64 + tloc);
      float4 lgv; lgv.x = L[0]; lgv.y = L[1]; lgv.z = L[2]; lgv.w = L[3];
      *(float4*)(outL + orow * NE + e0) = lgv;
      *(float4*)(outA + orow * NE + e0) = alv;
    }
  }
#undef XLOADV
#undef ASPLITV
#undef BSTAGE_H
#undef FRAG_READ
#undef MFMA12
#undef PH0
#undef PH1
}

extern "C" void kernel_launch(void* const* d_in, const int* in_sizes, int n_in,
                              void* d_out, int out_size, void* d_ws, size_t ws_size,
                              hipStream_t stream) {
  const float* x  = (const float*)d_in[0];
  const float* W1 = (const float*)d_in[1];
  const float* b1 = (const float*)d_in[2];
  const float* W2 = (const float*)d_in[3];
  const float* b2 = (const float*)d_in[4];
  _Float16* w1img = (_Float16*)d_ws;
  _Float16* w2t = w1img + (size_t)NCHUNK * (CH_BYTES / 2);
  float* outA = (float*)d_out;
  const size_t n_tok = (size_t)in_sizes[0] / KDIM;
  float* outL = outA + n_tok * NE;

  prep_w1<<<dim3(128), dim3(256), 0, stream>>>(W1, w1img);
  prep_w2<<<dim3(16), dim3(256), 0, stream>>>(W2, w2t);

  hipFuncSetAttribute((const void*)fused_router,
                      hipFuncAttributeMaxDynamicSharedMemorySize, SMEM_BYTES);
  fused_router<<<dim3((unsigned)(n_tok / ROWS_BLK)), dim3(512), SMEM_BYTES, stream>>>(
      x, w1img, w2t, b1, b2, outA, outL);
}